// Round 1
// baseline (143.001 us; speedup 1.0000x reference)
//
#include <hip/hip_runtime.h>
#include <hip/hip_fp16.h>

namespace {
constexpr int G = 33;
constexpr int GG = G * G;            // 1089
constexpr int NENT = G * G * G;      // 35937
constexpr int NB = 8;
constexpr size_t HW = 1024ull * 1024ull;
constexpr int GROUPS_PER_BATCH = (int)(HW / 4);        // 262144 (4 px per thread)
constexpr int TOTAL_GROUPS = NB * GROUPS_PER_BATCH;    // 2097152
}

union PackEntry {
    uint4 u;
    __half h[8];
};

// Pack each (b,x,y,z) z-pair {lut[z], lut[z+1]} into one 16B fp16 entry.
__global__ __launch_bounds__(256) void lut_pack(const float* __restrict__ lut,
                                                uint4* __restrict__ packed) {
    int i = blockIdx.x * 256 + threadIdx.x;
    if (i >= NB * NENT) return;
    int p = i % NENT;
    int z = p % G;
    const float* s = lut + (size_t)i * 3;
    float c0r = s[0], c0g = s[1], c0b = s[2];
    float c1r, c1g, c1b;
    if (z < G - 1) { c1r = s[3]; c1g = s[4]; c1b = s[5]; }
    else           { c1r = c0r;  c1g = c0g;  c1b = c0b; }   // never read, keep valid
    PackEntry e;
    e.h[0] = __float2half_rn(c0r);
    e.h[1] = __float2half_rn(c0g);
    e.h[2] = __float2half_rn(c0b);
    e.h[3] = __float2half_rn(c1r);
    e.h[4] = __float2half_rn(c1g);
    e.h[5] = __float2half_rn(c1b);
    e.h[6] = __float2half_rn(0.0f);
    e.h[7] = __float2half_rn(0.0f);
    packed[i] = e.u;
}

// z-lerp one packed corner pair -> 3 channel values
__device__ __forceinline__ void zlerp(uint4 q, float zd, float* o) {
    const __half2* h = reinterpret_cast<const __half2*>(&q);
    float2 v0 = __half22float2(h[0]);   // c0r, c0g
    float2 v1 = __half22float2(h[1]);   // c0b, c1r
    float2 v2 = __half22float2(h[2]);   // c1g, c1b
    o[0] = v0.x + zd * (v1.y - v0.x);
    o[1] = v0.y + zd * (v2.x - v0.y);
    o[2] = v1.x + zd * (v2.y - v1.x);
}

__global__ __launch_bounds__(256) void lut_apply(const float* __restrict__ img,
                                                 const uint4* __restrict__ packed,
                                                 float* __restrict__ out) {
    // XCD-chunk swizzle: gridDim.x == 8192 (divisible by 8); each XCD gets a
    // contiguous chunk -> exactly one batch's 575KB table per XCD L2.
    int bid = blockIdx.x;
    int cpx = gridDim.x >> 3;
    int swz = (bid & 7) * cpx + (bid >> 3);
    int gid = swz * 256 + threadIdx.x;

    int b = gid / GROUPS_PER_BATCH;
    int rem = gid - b * GROUPS_PER_BATCH;
    size_t base = (size_t)b * 3 * HW + (size_t)rem * 4;

    const float4 r4 = *reinterpret_cast<const float4*>(img + base);
    const float4 g4 = *reinterpret_cast<const float4*>(img + base + HW);
    const float4 b4 = *reinterpret_cast<const float4*>(img + base + 2 * HW);

    const uint4* tab = packed + (size_t)b * NENT;

    float R[4]  = {r4.x, r4.y, r4.z, r4.w};
    float Gc[4] = {g4.x, g4.y, g4.z, g4.w};
    float Bc[4] = {b4.x, b4.y, b4.z, b4.w};
    float OR[4], OG[4], OB[4];

#pragma unroll
    for (int k = 0; k < 4; ++k) {
        float x = fminf(fmaxf(R[k]  * 32.0f, 0.0f), 31.999998f);
        float y = fminf(fmaxf(Gc[k] * 32.0f, 0.0f), 31.999998f);
        float z = fminf(fmaxf(Bc[k] * 32.0f, 0.0f), 31.999998f);
        int x0 = (int)x, y0 = (int)y, z0 = (int)z;
        float xd = x - (float)x0, yd = y - (float)y0, zd = z - (float)z0;

        int p = (x0 * G + y0) * G + z0;
        uint4 q00 = tab[p];            // (x0,y0) z-pair
        uint4 q10 = tab[p + GG];       // (x1,y0)
        uint4 q01 = tab[p + G];        // (x0,y1)
        uint4 q11 = tab[p + GG + G];   // (x1,y1)

        float c00[3], c10[3], c01[3], c11[3];
        zlerp(q00, zd, c00);
        zlerp(q10, zd, c10);
        zlerp(q01, zd, c01);
        zlerp(q11, zd, c11);

        float a0r = c00[0] + xd * (c10[0] - c00[0]);
        float a1r = c01[0] + xd * (c11[0] - c01[0]);
        OR[k] = a0r + yd * (a1r - a0r);
        float a0g = c00[1] + xd * (c10[1] - c00[1]);
        float a1g = c01[1] + xd * (c11[1] - c01[1]);
        OG[k] = a0g + yd * (a1g - a0g);
        float a0b = c00[2] + xd * (c10[2] - c00[2]);
        float a1b = c01[2] + xd * (c11[2] - c01[2]);
        OB[k] = a0b + yd * (a1b - a0b);
    }

    *reinterpret_cast<float4*>(out + base)          = make_float4(OR[0], OR[1], OR[2], OR[3]);
    *reinterpret_cast<float4*>(out + base + HW)     = make_float4(OG[0], OG[1], OG[2], OG[3]);
    *reinterpret_cast<float4*>(out + base + 2 * HW) = make_float4(OB[0], OB[1], OB[2], OB[3]);
}

// Fallback if d_ws can't hold the packed table: gather f32 LUT directly.
__global__ __launch_bounds__(256) void lut_apply_f32(const float* __restrict__ img,
                                                     const float* __restrict__ lut,
                                                     float* __restrict__ out) {
    int bid = blockIdx.x;
    int cpx = gridDim.x >> 3;
    int swz = (bid & 7) * cpx + (bid >> 3);
    int gid = swz * 256 + threadIdx.x;

    int b = gid / GROUPS_PER_BATCH;
    int rem = gid - b * GROUPS_PER_BATCH;
    size_t base = (size_t)b * 3 * HW + (size_t)rem * 4;

    const float4 r4 = *reinterpret_cast<const float4*>(img + base);
    const float4 g4 = *reinterpret_cast<const float4*>(img + base + HW);
    const float4 b4 = *reinterpret_cast<const float4*>(img + base + 2 * HW);

    const float* tab = lut + (size_t)b * NENT * 3;

    float R[4]  = {r4.x, r4.y, r4.z, r4.w};
    float Gc[4] = {g4.x, g4.y, g4.z, g4.w};
    float Bc[4] = {b4.x, b4.y, b4.z, b4.w};
    float OR[4], OG[4], OB[4];

#pragma unroll
    for (int k = 0; k < 4; ++k) {
        float x = fminf(fmaxf(R[k]  * 32.0f, 0.0f), 31.999998f);
        float y = fminf(fmaxf(Gc[k] * 32.0f, 0.0f), 31.999998f);
        float z = fminf(fmaxf(Bc[k] * 32.0f, 0.0f), 31.999998f);
        int x0 = (int)x, y0 = (int)y, z0 = (int)z;
        float xd = x - (float)x0, yd = y - (float)y0, zd = z - (float)z0;

        int p = (x0 * G + y0) * G + z0;
        const float* e00 = tab + (size_t)p * 3;
        const float* e10 = tab + (size_t)(p + GG) * 3;
        const float* e01 = tab + (size_t)(p + G) * 3;
        const float* e11 = tab + (size_t)(p + GG + G) * 3;

        float c00[3], c10[3], c01[3], c11[3];
#pragma unroll
        for (int c = 0; c < 3; ++c) {
            c00[c] = e00[c] + zd * (e00[c + 3] - e00[c]);
            c10[c] = e10[c] + zd * (e10[c + 3] - e10[c]);
            c01[c] = e01[c] + zd * (e01[c + 3] - e01[c]);
            c11[c] = e11[c] + zd * (e11[c + 3] - e11[c]);
        }
        float a0r = c00[0] + xd * (c10[0] - c00[0]);
        float a1r = c01[0] + xd * (c11[0] - c01[0]);
        OR[k] = a0r + yd * (a1r - a0r);
        float a0g = c00[1] + xd * (c10[1] - c00[1]);
        float a1g = c01[1] + xd * (c11[1] - c01[1]);
        OG[k] = a0g + yd * (a1g - a0g);
        float a0b = c00[2] + xd * (c10[2] - c00[2]);
        float a1b = c01[2] + xd * (c11[2] - c01[2]);
        OB[k] = a0b + yd * (a1b - a0b);
    }

    *reinterpret_cast<float4*>(out + base)          = make_float4(OR[0], OR[1], OR[2], OR[3]);
    *reinterpret_cast<float4*>(out + base + HW)     = make_float4(OG[0], OG[1], OG[2], OG[3]);
    *reinterpret_cast<float4*>(out + base + 2 * HW) = make_float4(OB[0], OB[1], OB[2], OB[3]);
}

extern "C" void kernel_launch(void* const* d_in, const int* in_sizes, int n_in,
                              void* d_out, int out_size, void* d_ws, size_t ws_size,
                              hipStream_t stream) {
    const float* img = (const float*)d_in[0];
    const float* lut = (const float*)d_in[1];
    float* out = (float*)d_out;

    size_t need = (size_t)NB * NENT * sizeof(uint4);   // 4.6 MB
    if (ws_size >= need) {
        uint4* packed = (uint4*)d_ws;
        int n = NB * NENT;
        lut_pack<<<(n + 255) / 256, 256, 0, stream>>>(lut, packed);
        lut_apply<<<TOTAL_GROUPS / 256, 256, 0, stream>>>(img, packed, out);
    } else {
        lut_apply_f32<<<TOTAL_GROUPS / 256, 256, 0, stream>>>(img, lut, out);
    }
}

// Round 2
// 52.505 us; speedup vs baseline: 2.7236x; 2.7236x over previous
//
#include <hip/hip_runtime.h>

namespace {
constexpr int G = 33;
constexpr int GG = G * G;            // 1089
constexpr int NENT = G * G * G;      // 35937
constexpr int NB = 8;
constexpr size_t HW = 1024ull * 1024ull;

constexpr int BLOCK = 1024;
constexpr int PX_PER_THREAD = 16;
constexpr int PX_PER_BLOCK = BLOCK * PX_PER_THREAD;          // 16384
constexpr int NBLOCKS = (int)(NB * HW / PX_PER_BLOCK);       // 512
constexpr int BLOCKS_PER_BATCH = (int)(HW / PX_PER_BLOCK);   // 64
}

// Pack lut (B,33,33,33,3) f32 -> u32 10:10:10 per entry.
__global__ __launch_bounds__(256) void lut_pack10(const float* __restrict__ lut,
                                                  unsigned int* __restrict__ packed) {
    int i = blockIdx.x * 256 + threadIdx.x;
    if (i >= NB * NENT) return;
    const float* s = lut + (size_t)i * 3;
    unsigned int r = (unsigned int)(fminf(fmaxf(s[0], 0.0f), 1.0f) * 1023.0f + 0.5f);
    unsigned int g = (unsigned int)(fminf(fmaxf(s[1], 0.0f), 1.0f) * 1023.0f + 0.5f);
    unsigned int b = (unsigned int)(fminf(fmaxf(s[2], 0.0f), 1.0f) * 1023.0f + 0.5f);
    packed[i] = r | (g << 10) | (b << 20);
}

__device__ __forceinline__ void unpack10(unsigned int w, float& r, float& g, float& b) {
    r = (float)(w & 1023u);
    g = (float)((w >> 10) & 1023u);
    b = (float)((w >> 20) & 1023u);
}

__global__ __launch_bounds__(BLOCK, 4) void lut_apply_lds(const float* __restrict__ img,
                                                          const unsigned int* __restrict__ packed,
                                                          float* __restrict__ out) {
    __shared__ unsigned int s_lut[NENT];   // 143,748 B of the 160 KiB LDS

    // XCD-chunk swizzle: 512 blocks / 8 XCDs = 64 contiguous per XCD = one batch.
    int bid = blockIdx.x;
    int swz = (bid & 7) * (NBLOCKS >> 3) + (bid >> 3);
    int b   = swz / BLOCKS_PER_BATCH;
    int blk = swz - b * BLOCKS_PER_BATCH;

    const unsigned int* gtab = packed + (size_t)b * NENT;
    int t = threadIdx.x;

    // Stage table to LDS: 8984 x 16B chunks + 1 tail word.
    {
        const uint4* g4 = reinterpret_cast<const uint4*>(gtab);
        uint4* s4 = reinterpret_cast<uint4*>(s_lut);
        for (int i = t; i < NENT / 4; i += BLOCK) s4[i] = g4[i];
        if (t == 0) s_lut[NENT - 1] = gtab[NENT - 1];
    }
    __syncthreads();

    const size_t ch_base = (size_t)b * 3 * HW + (size_t)blk * PX_PER_BLOCK;

#pragma unroll
    for (int grp = 0; grp < PX_PER_THREAD / 4; ++grp) {
        size_t off = ch_base + (size_t)grp * (BLOCK * 4) + (size_t)t * 4;

        const float4 r4 = *reinterpret_cast<const float4*>(img + off);
        const float4 g4 = *reinterpret_cast<const float4*>(img + off + HW);
        const float4 b4 = *reinterpret_cast<const float4*>(img + off + 2 * HW);

        float R[4]  = {r4.x, r4.y, r4.z, r4.w};
        float Gc[4] = {g4.x, g4.y, g4.z, g4.w};
        float Bc[4] = {b4.x, b4.y, b4.z, b4.w};
        float OR[4], OG[4], OB[4];

#pragma unroll
        for (int k = 0; k < 4; ++k) {
            float x = fminf(fmaxf(R[k]  * 32.0f, 0.0f), 31.999998f);
            float y = fminf(fmaxf(Gc[k] * 32.0f, 0.0f), 31.999998f);
            float z = fminf(fmaxf(Bc[k] * 32.0f, 0.0f), 31.999998f);
            int x0 = (int)x, y0 = (int)y, z0 = (int)z;
            float xd = x - (float)x0, yd = y - (float)y0, zd = z - (float)z0;

            int p = x0 * GG + y0 * G + z0;

            unsigned int w000 = s_lut[p];
            unsigned int w001 = s_lut[p + 1];
            unsigned int w010 = s_lut[p + G];
            unsigned int w011 = s_lut[p + G + 1];
            unsigned int w100 = s_lut[p + GG];
            unsigned int w101 = s_lut[p + GG + 1];
            unsigned int w110 = s_lut[p + GG + G];
            unsigned int w111 = s_lut[p + GG + G + 1];

            float r000, g000, b000, r001, g001, b001;
            float r010, g010, b010, r011, g011, b011;
            float r100, g100, b100, r101, g101, b101;
            float r110, g110, b110, r111, g111, b111;
            unpack10(w000, r000, g000, b000);
            unpack10(w001, r001, g001, b001);
            unpack10(w010, r010, g010, b010);
            unpack10(w011, r011, g011, b011);
            unpack10(w100, r100, g100, b100);
            unpack10(w101, r101, g101, b101);
            unpack10(w110, r110, g110, b110);
            unpack10(w111, r111, g111, b111);

            // z-lerp the 4 corner pairs
            float c00r = r000 + zd * (r001 - r000);
            float c00g = g000 + zd * (g001 - g000);
            float c00b = b000 + zd * (b001 - b000);
            float c01r = r010 + zd * (r011 - r010);
            float c01g = g010 + zd * (g011 - g010);
            float c01b = b010 + zd * (b011 - b010);
            float c10r = r100 + zd * (r101 - r100);
            float c10g = g100 + zd * (g101 - g100);
            float c10b = b100 + zd * (b101 - b100);
            float c11r = r110 + zd * (r111 - r110);
            float c11g = g110 + zd * (g111 - g110);
            float c11b = b110 + zd * (b111 - b110);

            // x-lerp
            float a0r = c00r + xd * (c10r - c00r);
            float a0g = c00g + xd * (c10g - c00g);
            float a0b = c00b + xd * (c10b - c00b);
            float a1r = c01r + xd * (c11r - c01r);
            float a1g = c01g + xd * (c11g - c01g);
            float a1b = c01b + xd * (c11b - c01b);

            // y-lerp + dequant scale
            constexpr float S = 1.0f / 1023.0f;
            OR[k] = (a0r + yd * (a1r - a0r)) * S;
            OG[k] = (a0g + yd * (a1g - a0g)) * S;
            OB[k] = (a0b + yd * (a1b - a0b)) * S;
        }

        *reinterpret_cast<float4*>(out + off)          = make_float4(OR[0], OR[1], OR[2], OR[3]);
        *reinterpret_cast<float4*>(out + off + HW)     = make_float4(OG[0], OG[1], OG[2], OG[3]);
        *reinterpret_cast<float4*>(out + off + 2 * HW) = make_float4(OB[0], OB[1], OB[2], OB[3]);
    }
}

// Fallback if d_ws is too small: gather f32 LUT directly from global.
__global__ __launch_bounds__(256) void lut_apply_f32(const float* __restrict__ img,
                                                     const float* __restrict__ lut,
                                                     float* __restrict__ out) {
    int gid = blockIdx.x * 256 + threadIdx.x;
    int gpb = (int)(HW / 4);
    int b = gid / gpb;
    int rem = gid - b * gpb;
    size_t base = (size_t)b * 3 * HW + (size_t)rem * 4;

    const float4 r4 = *reinterpret_cast<const float4*>(img + base);
    const float4 g4 = *reinterpret_cast<const float4*>(img + base + HW);
    const float4 b4 = *reinterpret_cast<const float4*>(img + base + 2 * HW);

    const float* tab = lut + (size_t)b * NENT * 3;

    float R[4]  = {r4.x, r4.y, r4.z, r4.w};
    float Gc[4] = {g4.x, g4.y, g4.z, g4.w};
    float Bc[4] = {b4.x, b4.y, b4.z, b4.w};
    float OR[4], OG[4], OB[4];

#pragma unroll
    for (int k = 0; k < 4; ++k) {
        float x = fminf(fmaxf(R[k]  * 32.0f, 0.0f), 31.999998f);
        float y = fminf(fmaxf(Gc[k] * 32.0f, 0.0f), 31.999998f);
        float z = fminf(fmaxf(Bc[k] * 32.0f, 0.0f), 31.999998f);
        int x0 = (int)x, y0 = (int)y, z0 = (int)z;
        float xd = x - (float)x0, yd = y - (float)y0, zd = z - (float)z0;

        int p = (x0 * G + y0) * G + z0;
        const float* e00 = tab + (size_t)p * 3;
        const float* e10 = tab + (size_t)(p + GG) * 3;
        const float* e01 = tab + (size_t)(p + G) * 3;
        const float* e11 = tab + (size_t)(p + GG + G) * 3;

        float c00[3], c10[3], c01[3], c11[3];
#pragma unroll
        for (int c = 0; c < 3; ++c) {
            c00[c] = e00[c] + zd * (e00[c + 3] - e00[c]);
            c10[c] = e10[c] + zd * (e10[c + 3] - e10[c]);
            c01[c] = e01[c] + zd * (e01[c + 3] - e01[c]);
            c11[c] = e11[c] + zd * (e11[c + 3] - e11[c]);
        }
        float a0r = c00[0] + xd * (c10[0] - c00[0]);
        float a1r = c01[0] + xd * (c11[0] - c01[0]);
        OR[k] = a0r + yd * (a1r - a0r);
        float a0g = c00[1] + xd * (c10[1] - c00[1]);
        float a1g = c01[1] + xd * (c11[1] - c01[1]);
        OG[k] = a0g + yd * (a1g - a0g);
        float a0b = c00[2] + xd * (c10[2] - c00[2]);
        float a1b = c01[2] + xd * (c11[2] - c01[2]);
        OB[k] = a0b + yd * (a1b - a0b);
    }

    *reinterpret_cast<float4*>(out + base)          = make_float4(OR[0], OR[1], OR[2], OR[3]);
    *reinterpret_cast<float4*>(out + base + HW)     = make_float4(OG[0], OG[1], OG[2], OG[3]);
    *reinterpret_cast<float4*>(out + base + 2 * HW) = make_float4(OB[0], OB[1], OB[2], OB[3]);
}

extern "C" void kernel_launch(void* const* d_in, const int* in_sizes, int n_in,
                              void* d_out, int out_size, void* d_ws, size_t ws_size,
                              hipStream_t stream) {
    const float* img = (const float*)d_in[0];
    const float* lut = (const float*)d_in[1];
    float* out = (float*)d_out;

    size_t need = (size_t)NB * NENT * sizeof(unsigned int);   // 1.15 MB
    if (ws_size >= need) {
        unsigned int* packed = (unsigned int*)d_ws;
        int n = NB * NENT;
        lut_pack10<<<(n + 255) / 256, 256, 0, stream>>>(lut, packed);
        lut_apply_lds<<<NBLOCKS, BLOCK, 0, stream>>>(img, packed, out);
    } else {
        lut_apply_f32<<<(int)(NB * HW / 4 / 256), 256, 0, stream>>>(img, lut, out);
    }
}

// Round 3
// 51.953 us; speedup vs baseline: 2.7525x; 1.0106x over previous
//
#include <hip/hip_runtime.h>

namespace {
constexpr int G = 33;
constexpr int GG = G * G;            // 1089
constexpr int NENT = G * G * G;      // 35937
constexpr int NB = 8;
constexpr size_t HW = 1024ull * 1024ull;

constexpr int BLOCK = 1024;
constexpr int NBLOCKS = 256;                                  // 1 per CU, persistent
constexpr int BLOCKS_PER_BATCH = NBLOCKS / NB;                // 32
constexpr int PX_PER_BLOCK = (int)(HW / BLOCKS_PER_BATCH);    // 32768
constexpr int GROUP_PX = BLOCK * 4;                           // 4096 px per group
constexpr int NGROUPS = PX_PER_BLOCK / GROUP_PX;              // 8
}

// Pack lut (B,33,33,33,3) f32 -> u32 10:10:10 per entry.
__global__ __launch_bounds__(256) void lut_pack10(const float* __restrict__ lut,
                                                  unsigned int* __restrict__ packed) {
    int i = blockIdx.x * 256 + threadIdx.x;
    if (i >= NB * NENT) return;
    const float* s = lut + (size_t)i * 3;
    unsigned int r = (unsigned int)(fminf(fmaxf(s[0], 0.0f), 1.0f) * 1023.0f + 0.5f);
    unsigned int g = (unsigned int)(fminf(fmaxf(s[1], 0.0f), 1.0f) * 1023.0f + 0.5f);
    unsigned int b = (unsigned int)(fminf(fmaxf(s[2], 0.0f), 1.0f) * 1023.0f + 0.5f);
    packed[i] = r | (g << 10) | (b << 20);
}

__device__ __forceinline__ float4 ldf4(const float* p) {
    return *reinterpret_cast<const float4*>(p);
}

__global__ __launch_bounds__(BLOCK, 1) void lut_apply_lds(const float* __restrict__ img,
                                                          const unsigned int* __restrict__ packed,
                                                          float* __restrict__ out) {
    __shared__ unsigned int s_lut[NENT];   // 143,748 B

    // HW round-robins block b onto XCD b%8; map batch = b&7 so each XCD
    // serves exactly one batch (its 143.8KB table stays in that XCD's L2).
    int bid = blockIdx.x;
    int b   = bid & 7;                 // batch
    int blk = bid >> 3;                // 0..31 within batch

    const unsigned int* gtab = packed + (size_t)b * NENT;
    int t = threadIdx.x;

    // Stage table to LDS once.
    {
        const uint4* g4 = reinterpret_cast<const uint4*>(gtab);
        uint4* s4 = reinterpret_cast<uint4*>(s_lut);
        for (int i = t; i < NENT / 4; i += BLOCK) s4[i] = g4[i];
        if (t == 0) s_lut[NENT - 1] = gtab[NENT - 1];
    }
    __syncthreads();

    const size_t ch_base = (size_t)b * 3 * HW + (size_t)blk * PX_PER_BLOCK;
    const float* imgR = img + ch_base;
    const float* imgG = imgR + HW;
    const float* imgB = imgR + 2 * HW;
    float* outR = out + ch_base;
    float* outG = outR + HW;
    float* outB = outR + 2 * HW;

    // Software pipeline: prefetch group g+1's img while computing group g.
    size_t off = (size_t)t * 4;
    float4 cr = ldf4(imgR + off);
    float4 cg = ldf4(imgG + off);
    float4 cb = ldf4(imgB + off);

    for (int g = 0; g < NGROUPS; ++g) {
        float4 nr, ng, nb;
        size_t noff = off + GROUP_PX;
        if (g < NGROUPS - 1) {
            nr = ldf4(imgR + noff);
            ng = ldf4(imgG + noff);
            nb = ldf4(imgB + noff);
        }

        float R[4]  = {cr.x, cr.y, cr.z, cr.w};
        float Gc[4] = {cg.x, cg.y, cg.z, cg.w};
        float Bc[4] = {cb.x, cb.y, cb.z, cb.w};

        // Phase 1: all indices + fractions for the 4 px.
        int   p[4];
        float xd[4], yd[4], zd[4];
#pragma unroll
        for (int k = 0; k < 4; ++k) {
            float x = fminf(fmaxf(R[k]  * 32.0f, 0.0f), 31.999998f);
            float y = fminf(fmaxf(Gc[k] * 32.0f, 0.0f), 31.999998f);
            float z = fminf(fmaxf(Bc[k] * 32.0f, 0.0f), 31.999998f);
            int x0 = (int)x, y0 = (int)y, z0 = (int)z;
            xd[k] = x - (float)x0;
            yd[k] = y - (float)y0;
            zd[k] = z - (float)z0;
            p[k] = x0 * GG + y0 * G + z0;
        }

        // Phase 2: all 32 LDS reads (pairs -> ds_read2_b32).
        unsigned int w[4][8];
#pragma unroll
        for (int k = 0; k < 4; ++k) {
            int q = p[k];
            w[k][0] = s_lut[q];
            w[k][1] = s_lut[q + 1];
            w[k][2] = s_lut[q + G];
            w[k][3] = s_lut[q + G + 1];
            w[k][4] = s_lut[q + GG];
            w[k][5] = s_lut[q + GG + 1];
            w[k][6] = s_lut[q + GG + G];
            w[k][7] = s_lut[q + GG + G + 1];
        }

        // Phase 3: unpack + lerp.
        float OR[4], OG[4], OB[4];
#pragma unroll
        for (int k = 0; k < 4; ++k) {
            float rc[8], gc[8], bc[8];
#pragma unroll
            for (int c = 0; c < 8; ++c) {
                unsigned int v = w[k][c];
                rc[c] = (float)(v & 1023u);
                gc[c] = (float)((v >> 10) & 1023u);
                bc[c] = (float)((v >> 20) & 1023u);
            }
            float z = zd[k], x = xd[k], y = yd[k];
            // z-lerp (pairs 0-1, 2-3, 4-5, 6-7)
            float c00r = rc[0] + z * (rc[1] - rc[0]);
            float c01r = rc[2] + z * (rc[3] - rc[2]);
            float c10r = rc[4] + z * (rc[5] - rc[4]);
            float c11r = rc[6] + z * (rc[7] - rc[6]);
            float c00g = gc[0] + z * (gc[1] - gc[0]);
            float c01g = gc[2] + z * (gc[3] - gc[2]);
            float c10g = gc[4] + z * (gc[5] - gc[4]);
            float c11g = gc[6] + z * (gc[7] - gc[6]);
            float c00b = bc[0] + z * (bc[1] - bc[0]);
            float c01b = bc[2] + z * (bc[3] - bc[2]);
            float c10b = bc[4] + z * (bc[5] - bc[4]);
            float c11b = bc[6] + z * (bc[7] - bc[6]);
            // x-lerp
            float a0r = c00r + x * (c10r - c00r);
            float a1r = c01r + x * (c11r - c01r);
            float a0g = c00g + x * (c10g - c00g);
            float a1g = c01g + x * (c11g - c01g);
            float a0b = c00b + x * (c10b - c00b);
            float a1b = c01b + x * (c11b - c01b);
            // y-lerp + dequant
            constexpr float S = 1.0f / 1023.0f;
            OR[k] = (a0r + y * (a1r - a0r)) * S;
            OG[k] = (a0g + y * (a1g - a0g)) * S;
            OB[k] = (a0b + y * (a1b - a0b)) * S;
        }

        *reinterpret_cast<float4*>(outR + off) = make_float4(OR[0], OR[1], OR[2], OR[3]);
        *reinterpret_cast<float4*>(outG + off) = make_float4(OG[0], OG[1], OG[2], OG[3]);
        *reinterpret_cast<float4*>(outB + off) = make_float4(OB[0], OB[1], OB[2], OB[3]);

        cr = nr; cg = ng; cb = nb;
        off = noff;
    }
}

// Fallback if d_ws is too small: gather f32 LUT directly from global.
__global__ __launch_bounds__(256) void lut_apply_f32(const float* __restrict__ img,
                                                     const float* __restrict__ lut,
                                                     float* __restrict__ out) {
    int gid = blockIdx.x * 256 + threadIdx.x;
    int gpb = (int)(HW / 4);
    int b = gid / gpb;
    int rem = gid - b * gpb;
    size_t base = (size_t)b * 3 * HW + (size_t)rem * 4;

    const float4 r4 = ldf4(img + base);
    const float4 g4 = ldf4(img + base + HW);
    const float4 b4 = ldf4(img + base + 2 * HW);

    const float* tab = lut + (size_t)b * NENT * 3;

    float R[4]  = {r4.x, r4.y, r4.z, r4.w};
    float Gc[4] = {g4.x, g4.y, g4.z, g4.w};
    float Bc[4] = {b4.x, b4.y, b4.z, b4.w};
    float OR[4], OG[4], OB[4];

#pragma unroll
    for (int k = 0; k < 4; ++k) {
        float x = fminf(fmaxf(R[k]  * 32.0f, 0.0f), 31.999998f);
        float y = fminf(fmaxf(Gc[k] * 32.0f, 0.0f), 31.999998f);
        float z = fminf(fmaxf(Bc[k] * 32.0f, 0.0f), 31.999998f);
        int x0 = (int)x, y0 = (int)y, z0 = (int)z;
        float xd = x - (float)x0, yd = y - (float)y0, zd = z - (float)z0;

        int p = (x0 * G + y0) * G + z0;
        const float* e00 = tab + (size_t)p * 3;
        const float* e10 = tab + (size_t)(p + GG) * 3;
        const float* e01 = tab + (size_t)(p + G) * 3;
        const float* e11 = tab + (size_t)(p + GG + G) * 3;

        float c00[3], c10[3], c01[3], c11[3];
#pragma unroll
        for (int c = 0; c < 3; ++c) {
            c00[c] = e00[c] + zd * (e00[c + 3] - e00[c]);
            c10[c] = e10[c] + zd * (e10[c + 3] - e10[c]);
            c01[c] = e01[c] + zd * (e01[c + 3] - e01[c]);
            c11[c] = e11[c] + zd * (e11[c + 3] - e11[c]);
        }
        float a0r = c00[0] + xd * (c10[0] - c00[0]);
        float a1r = c01[0] + xd * (c11[0] - c01[0]);
        OR[k] = a0r + yd * (a1r - a0r);
        float a0g = c00[1] + xd * (c10[1] - c00[1]);
        float a1g = c01[1] + xd * (c11[1] - c01[1]);
        OG[k] = a0g + yd * (a1g - a0g);
        float a0b = c00[2] + xd * (c10[2] - c00[2]);
        float a1b = c01[2] + xd * (c11[2] - c01[2]);
        OB[k] = a0b + yd * (a1b - a0b);
    }

    *reinterpret_cast<float4*>(out + base)          = make_float4(OR[0], OR[1], OR[2], OR[3]);
    *reinterpret_cast<float4*>(out + base + HW)     = make_float4(OG[0], OG[1], OG[2], OG[3]);
    *reinterpret_cast<float4*>(out + base + 2 * HW) = make_float4(OB[0], OB[1], OB[2], OB[3]);
}

extern "C" void kernel_launch(void* const* d_in, const int* in_sizes, int n_in,
                              void* d_out, int out_size, void* d_ws, size_t ws_size,
                              hipStream_t stream) {
    const float* img = (const float*)d_in[0];
    const float* lut = (const float*)d_in[1];
    float* out = (float*)d_out;

    size_t need = (size_t)NB * NENT * sizeof(unsigned int);   // 1.15 MB
    if (ws_size >= need) {
        unsigned int* packed = (unsigned int*)d_ws;
        int n = NB * NENT;
        lut_pack10<<<(n + 255) / 256, 256, 0, stream>>>(lut, packed);
        lut_apply_lds<<<NBLOCKS, BLOCK, 0, stream>>>(img, packed, out);
    } else {
        lut_apply_f32<<<(int)(NB * HW / 4 / 256), 256, 0, stream>>>(img, lut, out);
    }
}

// Round 4
// 46.347 us; speedup vs baseline: 3.0855x; 1.1210x over previous
//
#include <hip/hip_runtime.h>

namespace {
constexpr int G = 33;
constexpr int GG = G * G;            // 1089
constexpr int NENT = G * G * G;      // 35937
constexpr int NB = 8;
constexpr size_t HW = 1024ull * 1024ull;

constexpr int BLOCK = 1024;
constexpr int NBLOCKS = 256;                                  // 1 per CU, persistent
constexpr int BLOCKS_PER_BATCH = NBLOCKS / NB;                // 32
constexpr int PX_PER_BLOCK = (int)(HW / BLOCKS_PER_BATCH);    // 32768
constexpr int PXT = 8;                                        // px per thread per group
constexpr int GROUP_PX = BLOCK * PXT;                         // 8192
constexpr int NGROUPS = PX_PER_BLOCK / GROUP_PX;              // 4
constexpr int SUB = BLOCK * 4;                                // sub-tile stride (4096 px)
}

// Pack lut (B,33,33,33,3) f32 -> u32 RGBA8 (r | g<<8 | b<<16).
__global__ __launch_bounds__(256) void lut_pack8(const float* __restrict__ lut,
                                                 unsigned int* __restrict__ packed) {
    int i = blockIdx.x * 256 + threadIdx.x;
    if (i >= NB * NENT) return;
    const float* s = lut + (size_t)i * 3;
    unsigned int r = (unsigned int)(fminf(fmaxf(s[0], 0.0f), 1.0f) * 255.0f + 0.5f);
    unsigned int g = (unsigned int)(fminf(fmaxf(s[1], 0.0f), 1.0f) * 255.0f + 0.5f);
    unsigned int b = (unsigned int)(fminf(fmaxf(s[2], 0.0f), 1.0f) * 255.0f + 0.5f);
    packed[i] = r | (g << 8) | (b << 16);
}

__device__ __forceinline__ float4 ldf4(const float* p) {
    return *reinterpret_cast<const float4*>(p);
}

__global__ __launch_bounds__(BLOCK, 1) void lut_apply_lds(const float* __restrict__ img,
                                                          const unsigned int* __restrict__ packed,
                                                          float* __restrict__ out) {
    __shared__ unsigned int s_lut[NENT];   // 143,748 B

    // HW round-robins block b onto XCD b%8; batch = b&7 keeps each XCD on one
    // batch's table (L2-local staging).
    int bid = blockIdx.x;
    int b   = bid & 7;
    int blk = bid >> 3;

    const unsigned int* gtab = packed + (size_t)b * NENT;
    int t = threadIdx.x;

    const size_t ch_base = (size_t)b * 3 * HW + (size_t)blk * PX_PER_BLOCK;
    const float* imgR = img + ch_base;
    const float* imgG = imgR + HW;
    const float* imgB = imgR + 2 * HW;
    float* outR = out + ch_base;
    float* outG = outR + HW;
    float* outB = outR + 2 * HW;

    // Issue group 0's img loads BEFORE staging so they overlap the table fill.
    size_t off = (size_t)t * 4;
    float4 cr0 = ldf4(imgR + off),       cr1 = ldf4(imgR + off + SUB);
    float4 cg0 = ldf4(imgG + off),       cg1 = ldf4(imgG + off + SUB);
    float4 cb0 = ldf4(imgB + off),       cb1 = ldf4(imgB + off + SUB);

    // Stage table to LDS once.
    {
        const uint4* g4 = reinterpret_cast<const uint4*>(gtab);
        uint4* s4 = reinterpret_cast<uint4*>(s_lut);
        for (int i = t; i < NENT / 4; i += BLOCK) s4[i] = g4[i];
        if (t == 0) s_lut[NENT - 1] = gtab[NENT - 1];
    }
    __syncthreads();

    for (int g = 0; g < NGROUPS; ++g) {
        float4 nr0, nr1, ng0, ng1, nb0, nb1;
        size_t noff = off + GROUP_PX;
        if (g < NGROUPS - 1) {
            nr0 = ldf4(imgR + noff); nr1 = ldf4(imgR + noff + SUB);
            ng0 = ldf4(imgG + noff); ng1 = ldf4(imgG + noff + SUB);
            nb0 = ldf4(imgB + noff); nb1 = ldf4(imgB + noff + SUB);
        }

        float R[PXT]  = {cr0.x, cr0.y, cr0.z, cr0.w, cr1.x, cr1.y, cr1.z, cr1.w};
        float Gc[PXT] = {cg0.x, cg0.y, cg0.z, cg0.w, cg1.x, cg1.y, cg1.z, cg1.w};
        float Bc[PXT] = {cb0.x, cb0.y, cb0.z, cb0.w, cb1.x, cb1.y, cb1.z, cb1.w};

        // Phase 1: indices + fractions for all 8 px.
        int   p[PXT];
        float xd[PXT], yd[PXT], zd[PXT];
#pragma unroll
        for (int k = 0; k < PXT; ++k) {
            float x = fminf(fmaxf(R[k]  * 32.0f, 0.0f), 31.999998f);
            float y = fminf(fmaxf(Gc[k] * 32.0f, 0.0f), 31.999998f);
            float z = fminf(fmaxf(Bc[k] * 32.0f, 0.0f), 31.999998f);
            int x0 = (int)x, y0 = (int)y, z0 = (int)z;
            xd[k] = x - (float)x0;
            yd[k] = y - (float)y0;
            zd[k] = z - (float)z0;
            p[k] = x0 * GG + y0 * G + z0;
        }

        // Phase 2: all 64 LDS word reads (ds_read2_b32 pairs), 8 px in flight.
        unsigned int w[PXT][8];
#pragma unroll
        for (int k = 0; k < PXT; ++k) {
            int q = p[k];
            w[k][0] = s_lut[q];
            w[k][1] = s_lut[q + 1];
            w[k][2] = s_lut[q + G];
            w[k][3] = s_lut[q + G + 1];
            w[k][4] = s_lut[q + GG];
            w[k][5] = s_lut[q + GG + 1];
            w[k][6] = s_lut[q + GG + G];
            w[k][7] = s_lut[q + GG + G + 1];
        }

        // Phase 3: unpack (v_cvt_f32_ubyte) + lerp.
        float OR[PXT], OG[PXT], OB[PXT];
#pragma unroll
        for (int k = 0; k < PXT; ++k) {
            float rc[8], gc[8], bc[8];
#pragma unroll
            for (int c = 0; c < 8; ++c) {
                unsigned int v = w[k][c];
                rc[c] = (float)(v & 0xffu);          // v_cvt_f32_ubyte0
                gc[c] = (float)((v >> 8) & 0xffu);   // v_cvt_f32_ubyte1
                bc[c] = (float)((v >> 16) & 0xffu);  // v_cvt_f32_ubyte2
            }
            float z = zd[k], x = xd[k], y = yd[k];
            float c00r = rc[0] + z * (rc[1] - rc[0]);
            float c01r = rc[2] + z * (rc[3] - rc[2]);
            float c10r = rc[4] + z * (rc[5] - rc[4]);
            float c11r = rc[6] + z * (rc[7] - rc[6]);
            float c00g = gc[0] + z * (gc[1] - gc[0]);
            float c01g = gc[2] + z * (gc[3] - gc[2]);
            float c10g = gc[4] + z * (gc[5] - gc[4]);
            float c11g = gc[6] + z * (gc[7] - gc[6]);
            float c00b = bc[0] + z * (bc[1] - bc[0]);
            float c01b = bc[2] + z * (bc[3] - bc[2]);
            float c10b = bc[4] + z * (bc[5] - bc[4]);
            float c11b = bc[6] + z * (bc[7] - bc[6]);
            float a0r = c00r + x * (c10r - c00r);
            float a1r = c01r + x * (c11r - c01r);
            float a0g = c00g + x * (c10g - c00g);
            float a1g = c01g + x * (c11g - c01g);
            float a0b = c00b + x * (c10b - c00b);
            float a1b = c01b + x * (c11b - c01b);
            constexpr float S = 1.0f / 255.0f;
            OR[k] = (a0r + y * (a1r - a0r)) * S;
            OG[k] = (a0g + y * (a1g - a0g)) * S;
            OB[k] = (a0b + y * (a1b - a0b)) * S;
        }

        *reinterpret_cast<float4*>(outR + off)       = make_float4(OR[0], OR[1], OR[2], OR[3]);
        *reinterpret_cast<float4*>(outR + off + SUB) = make_float4(OR[4], OR[5], OR[6], OR[7]);
        *reinterpret_cast<float4*>(outG + off)       = make_float4(OG[0], OG[1], OG[2], OG[3]);
        *reinterpret_cast<float4*>(outG + off + SUB) = make_float4(OG[4], OG[5], OG[6], OG[7]);
        *reinterpret_cast<float4*>(outB + off)       = make_float4(OB[0], OB[1], OB[2], OB[3]);
        *reinterpret_cast<float4*>(outB + off + SUB) = make_float4(OB[4], OB[5], OB[6], OB[7]);

        cr0 = nr0; cr1 = nr1; cg0 = ng0; cg1 = ng1; cb0 = nb0; cb1 = nb1;
        off = noff;
    }
}

// Fallback if d_ws is too small: gather f32 LUT directly from global.
__global__ __launch_bounds__(256) void lut_apply_f32(const float* __restrict__ img,
                                                     const float* __restrict__ lut,
                                                     float* __restrict__ out) {
    int gid = blockIdx.x * 256 + threadIdx.x;
    int gpb = (int)(HW / 4);
    int b = gid / gpb;
    int rem = gid - b * gpb;
    size_t base = (size_t)b * 3 * HW + (size_t)rem * 4;

    const float4 r4 = ldf4(img + base);
    const float4 g4 = ldf4(img + base + HW);
    const float4 b4 = ldf4(img + base + 2 * HW);

    const float* tab = lut + (size_t)b * NENT * 3;

    float R[4]  = {r4.x, r4.y, r4.z, r4.w};
    float Gc[4] = {g4.x, g4.y, g4.z, g4.w};
    float Bc[4] = {b4.x, b4.y, b4.z, b4.w};
    float OR[4], OG[4], OB[4];

#pragma unroll
    for (int k = 0; k < 4; ++k) {
        float x = fminf(fmaxf(R[k]  * 32.0f, 0.0f), 31.999998f);
        float y = fminf(fmaxf(Gc[k] * 32.0f, 0.0f), 31.999998f);
        float z = fminf(fmaxf(Bc[k] * 32.0f, 0.0f), 31.999998f);
        int x0 = (int)x, y0 = (int)y, z0 = (int)z;
        float xd = x - (float)x0, yd = y - (float)y0, zd = z - (float)z0;

        int p = (x0 * G + y0) * G + z0;
        const float* e00 = tab + (size_t)p * 3;
        const float* e10 = tab + (size_t)(p + GG) * 3;
        const float* e01 = tab + (size_t)(p + G) * 3;
        const float* e11 = tab + (size_t)(p + GG + G) * 3;

        float c00[3], c10[3], c01[3], c11[3];
#pragma unroll
        for (int c = 0; c < 3; ++c) {
            c00[c] = e00[c] + zd * (e00[c + 3] - e00[c]);
            c10[c] = e10[c] + zd * (e10[c + 3] - e10[c]);
            c01[c] = e01[c] + zd * (e01[c + 3] - e01[c]);
            c11[c] = e11[c] + zd * (e11[c + 3] - e11[c]);
        }
        float a0r = c00[0] + xd * (c10[0] - c00[0]);
        float a1r = c01[0] + xd * (c11[0] - c01[0]);
        OR[k] = a0r + yd * (a1r - a0r);
        float a0g = c00[1] + xd * (c10[1] - c00[1]);
        float a1g = c01[1] + xd * (c11[1] - c01[1]);
        OG[k] = a0g + yd * (a1g - a0g);
        float a0b = c00[2] + xd * (c10[2] - c00[2]);
        float a1b = c01[2] + xd * (c11[2] - c01[2]);
        OB[k] = a0b + yd * (a1b - a0b);
    }

    *reinterpret_cast<float4*>(out + base)          = make_float4(OR[0], OR[1], OR[2], OR[3]);
    *reinterpret_cast<float4*>(out + base + HW)     = make_float4(OG[0], OG[1], OG[2], OG[3]);
    *reinterpret_cast<float4*>(out + base + 2 * HW) = make_float4(OB[0], OB[1], OB[2], OB[3]);
}

extern "C" void kernel_launch(void* const* d_in, const int* in_sizes, int n_in,
                              void* d_out, int out_size, void* d_ws, size_t ws_size,
                              hipStream_t stream) {
    const float* img = (const float*)d_in[0];
    const float* lut = (const float*)d_in[1];
    float* out = (float*)d_out;

    size_t need = (size_t)NB * NENT * sizeof(unsigned int);   // 1.15 MB
    if (ws_size >= need) {
        unsigned int* packed = (unsigned int*)d_ws;
        int n = NB * NENT;
        lut_pack8<<<(n + 255) / 256, 256, 0, stream>>>(lut, packed);
        lut_apply_lds<<<NBLOCKS, BLOCK, 0, stream>>>(img, packed, out);
    } else {
        lut_apply_f32<<<(int)(NB * HW / 4 / 256), 256, 0, stream>>>(img, lut, out);
    }
}